// Round 5
// baseline (1218.145 us; speedup 1.0000x reference)
//
#include <hip/hip_runtime.h>
#include <math.h>

#define NB   16
#define NBEF 512
#define NSTK 256
#define CCO  128
#define SPIN 512
#define SPOUT 256
#define DNIN 128
#define DNOUT 128
#define NPNT 32
#define SP_ELEMS (NB * SPOUT * NBEF)   // 2,097,152 f32 elems (sparse output)

__device__ __forceinline__ float gelu_tanh(float x) {
    float inner = 0.7978845608028654f * (x + 0.044715f * x * x * x);
    return 0.5f * x * (1.0f + tanhf(inner));
}

// serial top-2 scan over sd[0..255]; strict < keeps lowest index on ties,
// matching lax.top_k stable ordering. Emits idx pair + normalized inv-dist weights.
__device__ __forceinline__ void top2_scan(const float* sd, int2* oij, float2* owt) {
    float m0 = 3.4e38f, m1 = 3.4e38f;
    int j0 = 0, j1 = 0;
    for (int j = 0; j < NSTK; ++j) {
        float d = sd[j];
        if (d < m0)      { m1 = m0; j1 = j0; m0 = d; j0 = j; }
        else if (d < m1) { m1 = d; j1 = j; }
    }
    float q0 = 1.f / (m0 + 1e-8f);
    float q1 = 1.f / (m1 + 1e-8f);
    float s = q0 + q1;
    *oij = make_int2(j0, j1);
    *owt = make_float2(q0 / s, q1 / s);
}

// ---------------- Kernel A: fused sparse branch (kNN inline, NO workspace) ----------------
__global__ __launch_bounds__(256) void sparse_direct_kernel(
    const float* __restrict__ SF,            // [16][512][256]
    const float* __restrict__ w_sp,          // [256][512]
    const float* __restrict__ stk_coor,      // [16][256][128]
    const float* __restrict__ stk_coor_bef,  // [16][512][128]
    const float* __restrict__ b_sp, const float* __restrict__ gamma_sp,
    const float* __restrict__ beta_sp,
    float* __restrict__ out)                 // [16][256][512] f32
{
    int b = blockIdx.y;
    int n0 = blockIdx.x * 8;                 // grid.x = 64
    int tid = threadIdx.x;

    __shared__ float bef8[8][CCO];           // 4 KB
    __shared__ float sd8[8][NSTK];           // 8 KB
    __shared__ float fs[SPIN][8];            // 16 KB
    __shared__ int2   sij[8];
    __shared__ float2 swt[8];

    // stage 8 query rows
    for (int l = tid; l < 8 * CCO; l += 256) {
        int nn = l >> 7, c = l & 127;
        bef8[nn][c] = stk_coor_bef[((size_t)b * NBEF + n0 + nn) * CCO + c];
    }
    __syncthreads();

    // thread j computes d2 to stroke j for all 8 queries
    {
        int j = tid;
        const float* sp = stk_coor + ((size_t)b * NSTK + j) * CCO;
        float dot[8] = {0,0,0,0,0,0,0,0};
        float na[8]  = {0,0,0,0,0,0,0,0};
        float nrm = 0.f;
        for (int c = 0; c < CCO; c += 4) {
            float4 s = *reinterpret_cast<const float4*>(sp + c);
            nrm += s.x*s.x + s.y*s.y + s.z*s.z + s.w*s.w;
            #pragma unroll
            for (int nn = 0; nn < 8; ++nn) {
                float b0 = bef8[nn][c],   b1 = bef8[nn][c+1];
                float b2 = bef8[nn][c+2], b3 = bef8[nn][c+3];
                dot[nn] += b0*s.x + b1*s.y + b2*s.z + b3*s.w;
                na[nn]  += b0*b0 + b1*b1 + b2*b2 + b3*b3;
            }
        }
        #pragma unroll
        for (int nn = 0; nn < 8; ++nn) sd8[nn][j] = na[nn] + nrm - 2.f * dot[nn];
    }
    __syncthreads();
    if (tid < 8) top2_scan(sd8[tid], &sij[tid], &swt[tid]);
    __syncthreads();

    // stage interpolated features fs[c][nn]
    for (int l = tid; l < SPIN * 8; l += 256) {
        int c = l >> 3, nn = l & 7;
        int2  ij = sij[nn];
        float2 w = swt[nn];
        const float* row = SF + ((size_t)b * SPIN + c) * NSTK;
        fs[c][nn] = w.x * row[ij.x] + w.y * row[ij.y];
    }
    __syncthreads();

    int o = tid;
    float acc[8] = {0,0,0,0,0,0,0,0};
    const float4* wr4 = reinterpret_cast<const float4*>(w_sp + (size_t)o * SPIN);
    #pragma unroll 4
    for (int c4 = 0; c4 < SPIN / 4; ++c4) {
        float4 a = wr4[c4];
        int c = c4 * 4;
        #pragma unroll
        for (int nn = 0; nn < 8; ++nn)
            acc[nn] += a.x * fs[c][nn] + a.y * fs[c+1][nn]
                     + a.z * fs[c+2][nn] + a.w * fs[c+3][nn];
    }

    const float invs = 1.0f / sqrtf(1.0f + 1e-5f);
    float bias  = b_sp[o];
    float scale = gamma_sp[o] * invs;
    float beta  = beta_sp[o];
    float r[8];
    #pragma unroll
    for (int q = 0; q < 8; ++q)
        r[q] = gelu_tanh((acc[q] + bias) * scale + beta);
    float* dst = out + ((size_t)b * SPOUT + o) * NBEF + n0;
    *reinterpret_cast<float4*>(dst)     = make_float4(r[0], r[1], r[2], r[3]);
    *reinterpret_cast<float4*>(dst + 4) = make_float4(r[4], r[5], r[6], r[7]);
}

// ---------------- Kernel B: dense branch (kNN inline, NO workspace) ----------------
// x~[s], s in [0,16386): x~[s] = x[clamp(s-1,0,16383)], x flat l = n*32+sp.
// even t: y = sum_i x~[i,t/2]*W[i,o,3]     + x~[i,t/2+1]*W[i,o,1]
// odd  t: y = sum_i x~[i,(t+1)/2]*W[i,o,2] + x~[i,(t+3)/2]*W[i,o,0]
__global__ __launch_bounds__(256) void dense_kernel(
    const float* __restrict__ DF,            // [16][128][256][32]
    const float* __restrict__ w_ct,          // [128][128][4]
    const float* __restrict__ b_ct,
    const float* __restrict__ gamma_dn,
    const float* __restrict__ beta_dn,
    const float* __restrict__ stk_coor,      // [16][256][128]
    const float* __restrict__ stk_coor_bef,  // [16][512][128]
    float* __restrict__ outd)                // [16][128][32768] f32 (already offset)
{
    int n = blockIdx.x, b = blockIdx.y;
    int tid = threadIdx.x;

    __shared__ float bef3[3][CCO];           // 1.5 KB
    __shared__ float sd3[3][NSTK];           // 3 KB
    __shared__ int2   dij[3];
    __shared__ float2 dwt[3];
    __shared__ float xs[34 * 128];           // 17 KB, [sl][i] XOR-swizzled (16B gran)

    int npv = (n > 0) ? n - 1 : 0;
    int nnx = (n < NBEF - 1) ? n + 1 : NBEF - 1;

    for (int l = tid; l < 3 * CCO; l += 256) {
        int r = l >> 7, c = l & 127;
        int nr = (r == 0) ? npv : ((r == 1) ? n : nnx);
        bef3[r][c] = stk_coor_bef[((size_t)b * NBEF + nr) * CCO + c];
    }
    __syncthreads();

    {
        int j = tid;
        const float* spx = stk_coor + ((size_t)b * NSTK + j) * CCO;
        float dot[3] = {0,0,0}, na[3] = {0,0,0}, nrm = 0.f;
        for (int c = 0; c < CCO; c += 4) {
            float4 s = *reinterpret_cast<const float4*>(spx + c);
            nrm += s.x*s.x + s.y*s.y + s.z*s.z + s.w*s.w;
            #pragma unroll
            for (int r = 0; r < 3; ++r) {
                float b0 = bef3[r][c],   b1 = bef3[r][c+1];
                float b2 = bef3[r][c+2], b3 = bef3[r][c+3];
                dot[r] += b0*s.x + b1*s.y + b2*s.z + b3*s.w;
                na[r]  += b0*b0 + b1*b1 + b2*b2 + b3*b3;
            }
        }
        #pragma unroll
        for (int r = 0; r < 3; ++r) sd3[r][j] = na[r] + nrm - 2.f * dot[r];
    }
    __syncthreads();
    if (tid < 3) top2_scan(sd3[tid], &dij[tid], &dwt[tid]);
    __syncthreads();

    const float* DFb = DF + (size_t)b * (DNIN * NSTK * NPNT);
    int2  ij = dij[1];
    float2 wn = dwt[1];

    // stage sl = 1..32 (this stroke): addr = i*8192 + stroke*32 + sp
    {
        int sp = tid & 31;
        int ibase = tid >> 5;                // 0..7
        const float* r0 = DFb + (size_t)ij.x * NPNT + sp;
        const float* r1 = DFb + (size_t)ij.y * NPNT + sp;
        int sl = sp + 1;
        #pragma unroll
        for (int p = 0; p < 16; ++p) {
            int i = p * 8 + ibase;
            float v0 = r0[(size_t)i * 8192];
            float v1 = r1[(size_t)i * 8192];
            int col = ((i >> 2) ^ ((sl & 7) << 2));
            xs[sl * 128 + (col << 2) + (i & 3)] = wn.x * v0 + wn.y * v1;
        }
    }
    // boundary halo: sl=0 (stroke n-1, pt31) and sl=33 (stroke n+1, pt0), edge-clamped
    {
        int side = tid >> 7;
        int i = tid & 127;
        int r = side ? 2 : 0;
        int spb = side ? (n < NBEF - 1 ? 0 : 31) : (n > 0 ? 31 : 0);
        int2  ijb = dij[r];
        float2 wb = dwt[r];
        float v0 = DFb[(size_t)i * 8192 + (size_t)ijb.x * NPNT + spb];
        float v1 = DFb[(size_t)i * 8192 + (size_t)ijb.y * NPNT + spb];
        int sl = side ? 33 : 0;
        int col = ((i >> 2) ^ ((sl & 7) << 2));
        xs[sl * 128 + (col << 2) + (i & 3)] = wb.x * v0 + wb.y * v1;
    }
    __syncthreads();

    int osub = tid >> 3, tsub = tid & 7;     // 32 o-subtiles x 8 t-subtiles
    int o0 = osub * 4, U = tsub * 4;
    float acc[4][8];
    #pragma unroll
    for (int a = 0; a < 4; ++a)
        #pragma unroll
        for (int t = 0; t < 8; ++t) acc[a][t] = 0.f;

    for (int i0 = 0; i0 < 128; i0 += 4) {
        float4 xv4[6];
        #pragma unroll
        for (int q = 0; q < 6; ++q) {
            int sl = U + q;
            int col = ((i0 >> 2) ^ ((sl & 7) << 2));
            xv4[q] = *reinterpret_cast<const float4*>(&xs[sl * 128 + (col << 2)]);
        }
        const float* xv = reinterpret_cast<const float*>(xv4);
        #pragma unroll
        for (int oo = 0; oo < 4; ++oo) {
            #pragma unroll
            for (int ii = 0; ii < 4; ++ii) {
                int i = i0 + ii;
                float4 w = *reinterpret_cast<const float4*>(
                    w_ct + ((size_t)i * DNOUT + (o0 + oo)) * 4);  // (k0,k1,k2,k3)
                float x0 = xv[0*4+ii], x1 = xv[1*4+ii], x2 = xv[2*4+ii];
                float x3 = xv[3*4+ii], x4 = xv[4*4+ii], x5 = xv[5*4+ii];
                acc[oo][0] += x0 * w.w + x1 * w.y;
                acc[oo][1] += x1 * w.z + x2 * w.x;
                acc[oo][2] += x1 * w.w + x2 * w.y;
                acc[oo][3] += x2 * w.z + x3 * w.x;
                acc[oo][4] += x2 * w.w + x3 * w.y;
                acc[oo][5] += x3 * w.z + x4 * w.x;
                acc[oo][6] += x3 * w.w + x4 * w.y;
                acc[oo][7] += x4 * w.z + x5 * w.x;
            }
        }
    }

    const float invs = 1.0f / sqrtf(1.0f + 1e-5f);
    #pragma unroll
    for (int oo = 0; oo < 4; ++oo) {
        int o = o0 + oo;
        float bias = b_ct[o];
        float scale = gamma_dn[o] * invs;
        float beta = beta_dn[o];
        size_t base = ((size_t)(b * DNOUT + o) << 15) + (size_t)n * 64 + tsub * 8;
        float r[8];
        #pragma unroll
        for (int q = 0; q < 8; ++q)
            r[q] = gelu_tanh((acc[oo][q] + bias) * scale + beta);
        *reinterpret_cast<float4*>(outd + base)     = make_float4(r[0], r[1], r[2], r[3]);
        *reinterpret_cast<float4*>(outd + base + 4) = make_float4(r[4], r[5], r[6], r[7]);
    }
}

extern "C" void kernel_launch(void* const* d_in, const int* in_sizes, int n_in,
                              void* d_out, int out_size, void* d_ws, size_t ws_size,
                              hipStream_t stream) {
    const float* sparse_fea   = (const float*)d_in[0];
    const float* dense_fea    = (const float*)d_in[1];
    const float* stk_coor     = (const float*)d_in[2];
    const float* stk_coor_bef = (const float*)d_in[3];
    const float* w_sp     = (const float*)d_in[4];
    const float* b_sp     = (const float*)d_in[5];
    const float* gamma_sp = (const float*)d_in[6];
    const float* beta_sp  = (const float*)d_in[7];
    const float* w_ct     = (const float*)d_in[8];
    const float* b_ct     = (const float*)d_in[9];
    const float* gamma_dn = (const float*)d_in[10];
    const float* beta_dn  = (const float*)d_in[11];
    float* out = (float*)d_out;

    (void)d_ws; (void)ws_size;  // workspace intentionally unused

    sparse_direct_kernel<<<dim3(NBEF / 8, NB), 256, 0, stream>>>(
        sparse_fea, w_sp, stk_coor, stk_coor_bef, b_sp, gamma_sp, beta_sp, out);
    dense_kernel<<<dim3(NBEF, NB), 256, 0, stream>>>(
        dense_fea, w_ct, b_ct, gamma_dn, beta_dn, stk_coor, stk_coor_bef,
        out + SP_ELEMS);
}

// Round 6
// 557.545 us; speedup vs baseline: 2.1848x; 2.1848x over previous
//
#include <hip/hip_runtime.h>
#include <math.h>

#define NB   16
#define NBEF 512
#define NSTK 256
#define CCO  128
#define SPIN 512
#define SPOUT 256
#define DNIN 128
#define DNOUT 128
#define NPNT 32
#define SP_ELEMS (NB * SPOUT * NBEF)   // 2,097,152 f32 elems (sparse output)

typedef __attribute__((ext_vector_type(8))) short bf16x8v;   // 8 bf16 = 4 VGPR
typedef __attribute__((ext_vector_type(4))) float f32x4v;    // MFMA C/D

__device__ __forceinline__ unsigned short f32_to_bf16(float f) {
    unsigned int u = __float_as_uint(f);
    u += 0x7fffu + ((u >> 16) & 1u);     // round-to-nearest-even
    return (unsigned short)(u >> 16);
}

__device__ __forceinline__ float gelu_tanh(float x) {
    float inner = 0.7978845608028654f * (x + 0.044715f * x * x * x);
    return 0.5f * x * (1.0f + tanhf(inner));
}

// serial top-2 scan; strict < keeps lowest index on ties (lax.top_k stable order)
__device__ __forceinline__ void top2_scan(const float* sd, int2* oij, float2* owt) {
    float m0 = 3.4e38f, m1 = 3.4e38f;
    int j0 = 0, j1 = 0;
    for (int j = 0; j < NSTK; ++j) {
        float d = sd[j];
        if (d < m0)      { m1 = m0; j1 = j0; m0 = d; j0 = j; }
        else if (d < m1) { m1 = d; j1 = j; }
    }
    float q0 = 1.f / (m0 + 1e-8f);
    float q1 = 1.f / (m1 + 1e-8f);
    float s = q0 + q1;
    *oij = make_int2(j0, j1);
    *owt = make_float2(q0 / s, q1 / s);
}

// ---------------- Kernel 0: 2-NN + weights -> workspace ----------------
__global__ __launch_bounds__(256) void knn_kernel(
    const float* __restrict__ stk_coor,      // [B][256][128]
    const float* __restrict__ stk_coor_bef,  // [B][512][128]
    int2* __restrict__ idx_out,              // [B][512]
    float2* __restrict__ w_out)              // [B][512]
{
    int n = blockIdx.x, b = blockIdx.y;
    int tid = threadIdx.x;

    __shared__ float bef[CCO];
    __shared__ float sd[256];

    const float* befp = stk_coor_bef + ((size_t)b * NBEF + n) * CCO;
    if (tid < CCO) bef[tid] = befp[tid];
    __syncthreads();

    const float* sp = stk_coor + ((size_t)b * NSTK + tid) * CCO;
    float dot = 0.f, na = 0.f, nb = 0.f;
    #pragma unroll 8
    for (int c = 0; c < CCO; c += 4) {
        float4 s = *reinterpret_cast<const float4*>(sp + c);
        float b0 = bef[c], b1 = bef[c+1], b2 = bef[c+2], b3 = bef[c+3];
        dot += b0*s.x + b1*s.y + b2*s.z + b3*s.w;
        na  += b0*b0 + b1*b1 + b2*b2 + b3*b3;
        nb  += s.x*s.x + s.y*s.y + s.z*s.z + s.w*s.w;
    }
    sd[tid] = na + nb - 2.f * dot;
    __syncthreads();
    if (tid == 0) {
        int2 ij; float2 w;
        top2_scan(sd, &ij, &w);
        idx_out[b * NBEF + n] = ij;
        w_out[b * NBEF + n]   = w;
    }
}

// ---------------- Kernel A: fused sparse branch (reads ws kNN) ----------------
__global__ __launch_bounds__(256) void sparse_direct_kernel(
    const float* __restrict__ SF,            // [16][512][256]
    const float* __restrict__ w_sp,          // [256][512]
    const int2* __restrict__ idxws, const float2* __restrict__ wgtws,
    const float* __restrict__ b_sp, const float* __restrict__ gamma_sp,
    const float* __restrict__ beta_sp,
    float* __restrict__ out)                 // [16][256][512] f32
{
    int b = blockIdx.y;
    int n0 = blockIdx.x * 8;                 // grid.x = 64
    int tid = threadIdx.x;

    __shared__ float fs[SPIN][8];            // 16 KB
    __shared__ int2   sij[8];
    __shared__ float2 swt[8];

    if (tid < 8) {
        sij[tid] = idxws[b * NBEF + n0 + tid];
        swt[tid] = wgtws[b * NBEF + n0 + tid];
    }
    __syncthreads();

    for (int l = tid; l < SPIN * 8; l += 256) {
        int c = l >> 3, nn = l & 7;
        int2  ij = sij[nn];
        float2 w = swt[nn];
        const float* row = SF + ((size_t)b * SPIN + c) * NSTK;
        fs[c][nn] = w.x * row[ij.x] + w.y * row[ij.y];
    }
    __syncthreads();

    int o = tid;
    float acc[8] = {0,0,0,0,0,0,0,0};
    const float4* wr4 = reinterpret_cast<const float4*>(w_sp + (size_t)o * SPIN);
    #pragma unroll 4
    for (int c4 = 0; c4 < SPIN / 4; ++c4) {
        float4 a = wr4[c4];
        int c = c4 * 4;
        #pragma unroll
        for (int nn = 0; nn < 8; ++nn)
            acc[nn] += a.x * fs[c][nn] + a.y * fs[c+1][nn]
                     + a.z * fs[c+2][nn] + a.w * fs[c+3][nn];
    }

    const float invs = 1.0f / sqrtf(1.0f + 1e-5f);
    float bias  = b_sp[o];
    float scale = gamma_sp[o] * invs;
    float beta  = beta_sp[o];
    float r[8];
    #pragma unroll
    for (int q = 0; q < 8; ++q)
        r[q] = gelu_tanh((acc[q] + bias) * scale + beta);
    float* dst = out + ((size_t)b * SPOUT + o) * NBEF + n0;
    *reinterpret_cast<float4*>(dst)     = make_float4(r[0], r[1], r[2], r[3]);
    *reinterpret_cast<float4*>(dst + 4) = make_float4(r[4], r[5], r[6], r[7]);
}

// ---------------- Kernel B: dense branch via bf16 MFMA ----------------
// GEMM C[m,c] = sum_k A[m,k]*B[k,c], m,k in [0,256), c in [0,129):
//   A[m<128][k<128]=W[k][m][3]   A[m<128][k>=128]=W[k-128][m][1]
//   A[m>=128][k<128]=W[k][m-128][2]  A[m>=128][k>=128]=W[k-128][m-128][0]
//   B[k<128][c]=xt[k][S0+c]   B[k>=128][c]=xt[k-128][S0+c+1]
//   y[o, T0+2c]   = C[o, c]       (c in [0,128))
//   y[o, T0+2c+1] = C[128+o, c+1] (c in [0,128))
// xt[s] = interp_x[clamp(s-1, 0, 16383)]; per block xt cols S0..S0+129 -> LDS cols 0..129.
// LDS layout: bf16 col-major, 128 elems/col, chunk-swizzle: elem = col*128 + ((i>>3 ^ (col&15))<<3) + (i&7)
__global__ __launch_bounds__(512) void dense_mfma_kernel(
    const float* __restrict__ DF,            // [16][128][256][32]
    const float* __restrict__ w_ct,          // [128][128][4]
    const float* __restrict__ b_ct,
    const float* __restrict__ gamma_dn,
    const float* __restrict__ beta_dn,
    const int2* __restrict__ idxws, const float2* __restrict__ wgtws,
    float* __restrict__ outd)                // [16][128][32768] f32 (already offset)
{
    int blk = blockIdx.x;                    // 0..127 (4 strokes each)
    int b   = blockIdx.y;
    int n0  = blk * 4;
    int S0  = n0 * 32;
    int T0  = n0 * 64;
    int tid  = threadIdx.x;
    int lane = tid & 63;
    int wid  = tid >> 6;                     // 0..7

    __shared__ unsigned short Xs[146 * 128]; // 37376 B
    __shared__ int2   sij[6];
    __shared__ float2 swt[6];
    __shared__ float bnb[128], bns[128], bnt[128];

    const float invs = 1.0f / sqrtf(1.0f + 1e-5f);
    if (tid < 128) {
        bnb[tid] = b_ct[tid];
        bns[tid] = gamma_dn[tid] * invs;
        bnt[tid] = beta_dn[tid];
    }
    if (tid < 6) {
        int s = n0 - 1 + tid;
        s = (s < 0) ? 0 : ((s > NBEF - 1) ? NBEF - 1 : s);
        sij[tid] = idxws[b * NBEF + s];
        swt[tid] = wgtws[b * NBEF + s];
    }
    // zero-fill pad cols 130..145 (read by padded N-tiles, results masked)
    if (tid < 256) {
        uint4 z = make_uint4(0, 0, 0, 0);
        *reinterpret_cast<uint4*>(&Xs[130 * 128 + tid * 8]) = z;
    }
    __syncthreads();

    const float* DFb = DF + (size_t)b * (DNIN * NSTK * NPNT);

    // ---- stage core cols 1..128 (strokes n0..n0+3) ----
    {
        int sp = tid & 31, ig = tid >> 5;    // ig 0..15 -> i range ig*8..+8
        #pragma unroll
        for (int nl = 0; nl < 4; ++nl) {
            int2  ij = sij[nl + 1];
            float2 w = swt[nl + 1];
            const float* r0 = DFb + (size_t)ij.x * NPNT + sp;
            const float* r1 = DFb + (size_t)ij.y * NPNT + sp;
            int col = nl * 32 + sp + 1;
            unsigned short t8[8];
            #pragma unroll
            for (int p = 0; p < 8; ++p) {
                int i = ig * 8 + p;
                float v = w.x * r0[(size_t)i * 8192] + w.y * r1[(size_t)i * 8192];
                t8[p] = f32_to_bf16(v);
            }
            int dst = col * 128 + ((ig ^ (col & 15)) << 3);
            *reinterpret_cast<uint4*>(&Xs[dst]) = *reinterpret_cast<const uint4*>(t8);
        }
    }
    // ---- halo cols 0 and 129 (edge-clamped flat index) ----
    if (tid < 256) {
        int i    = tid & 127;
        int side = tid >> 7;
        int col  = side ? 129 : 0;
        int L    = side ? (S0 + 128) : (S0 - 1);
        L = (L < 0) ? 0 : ((L > 16383) ? 16383 : L);
        int stroke = L >> 5, pt = L & 31;
        int slot = stroke - (n0 - 1);        // consistent with clamped sij load
        int2  ij = sij[slot];
        float2 w = swt[slot];
        float v = w.x * DFb[(size_t)i * 8192 + (size_t)ij.x * NPNT + pt]
                + w.y * DFb[(size_t)i * 8192 + (size_t)ij.y * NPNT + pt];
        int dst = col * 128 + ((((i >> 3) ^ (col & 15))) << 3) + (i & 7);
        Xs[dst] = f32_to_bf16(v);
    }

    // ---- A fragments: wave wid owns m in [wid*32, wid*32+32), all 256 k ----
    int wm = wid * 32;
    int rit = lane & 15;                     // row in 16-tile
    int kgrp = lane >> 4;                    // 0..3
    bf16x8v afrag[2][8];
    #pragma unroll
    for (int mt = 0; mt < 2; ++mt) {
        int m = wm + mt * 16 + rit;
        int o = m & 127;
        int modd = (m >= 128);
        #pragma unroll
        for (int ks = 0; ks < 8; ++ks) {
            int kb = ks * 32 + kgrp * 8;
            unsigned short t8[8];
            #pragma unroll
            for (int j = 0; j < 8; ++j) {
                int k = kb + j;
                int i = k & 127;
                int tap = modd ? (k < 128 ? 2 : 0) : (k < 128 ? 3 : 1);
                t8[j] = f32_to_bf16(w_ct[((size_t)i * DNOUT + o) * 4 + tap]);
            }
            afrag[mt][ks] = *reinterpret_cast<const bf16x8v*>(t8);
        }
    }
    __syncthreads();

    // ---- MFMA main loop: 9 N-tiles x 8 K-steps x 2 M-tiles ----
    #pragma unroll 1
    for (int nt = 0; nt < 9; ++nt) {
        f32x4v acc0 = {0.f, 0.f, 0.f, 0.f};
        f32x4v acc1 = {0.f, 0.f, 0.f, 0.f};
        #pragma unroll
        for (int ks = 0; ks < 8; ++ks) {
            int kb   = ks * 32 + kgrp * 8;
            int half = kb >> 7;              // 0: lower K-half, 1: upper (col+1)
            int i    = kb & 127;
            int col  = nt * 16 + rit + half;
            int src  = col * 128 + ((((i >> 3) ^ (col & 15))) << 3);
            bf16x8v bfrag = *reinterpret_cast<const bf16x8v*>(&Xs[src]);
            acc0 = __builtin_amdgcn_mfma_f32_16x16x32_bf16(afrag[0][ks], bfrag, acc0, 0, 0, 0);
            acc1 = __builtin_amdgcn_mfma_f32_16x16x32_bf16(afrag[1][ks], bfrag, acc1, 0, 0, 0);
        }
        int c = nt * 16 + rit;               // C/D: col = lane&15
        #pragma unroll
        for (int mt = 0; mt < 2; ++mt) {
            #pragma unroll
            for (int q = 0; q < 4; ++q) {
                float v = mt ? acc1[q] : acc0[q];
                int m = wm + mt * 16 + kgrp * 4 + q;   // C/D: row = (lane>>4)*4+q
                int o = m & 127;
                int modd = (m >= 128);
                bool ok = modd ? (c >= 1 && c <= 128) : (c < 128);
                if (ok) {
                    int t = T0 + (modd ? 2 * (c - 1) + 1 : 2 * c);
                    float y = gelu_tanh((v + bnb[o]) * bns[o] + bnt[o]);
                    outd[(((size_t)b * DNOUT + o) << 15) + t] = y;
                }
            }
        }
    }
}

extern "C" void kernel_launch(void* const* d_in, const int* in_sizes, int n_in,
                              void* d_out, int out_size, void* d_ws, size_t ws_size,
                              hipStream_t stream) {
    const float* sparse_fea   = (const float*)d_in[0];
    const float* dense_fea    = (const float*)d_in[1];
    const float* stk_coor     = (const float*)d_in[2];
    const float* stk_coor_bef = (const float*)d_in[3];
    const float* w_sp     = (const float*)d_in[4];
    const float* b_sp     = (const float*)d_in[5];
    const float* gamma_sp = (const float*)d_in[6];
    const float* beta_sp  = (const float*)d_in[7];
    const float* w_ct     = (const float*)d_in[8];
    const float* b_ct     = (const float*)d_in[9];
    const float* gamma_dn = (const float*)d_in[10];
    const float* beta_dn  = (const float*)d_in[11];
    float* out = (float*)d_out;

    char* ws = (char*)d_ws;
    int2*   idx = (int2*)ws;                 // 64 KB
    float2* wgt = (float2*)(ws + 65536);     // 64 KB (total ws: 128 KB)

    knn_kernel<<<dim3(NBEF, NB), 256, 0, stream>>>(stk_coor, stk_coor_bef, idx, wgt);
    sparse_direct_kernel<<<dim3(NBEF / 8, NB), 256, 0, stream>>>(
        sparse_fea, w_sp, idx, wgt, b_sp, gamma_sp, beta_sp, out);
    dense_mfma_kernel<<<dim3(NBEF / 4, NB), 512, 0, stream>>>(
        dense_fea, w_ct, b_ct, gamma_dn, beta_dn, idx, wgt, out + SP_ELEMS);
}

// Round 7
// 413.838 us; speedup vs baseline: 2.9435x; 1.3473x over previous
//
#include <hip/hip_runtime.h>
#include <math.h>

#define NB   16
#define NBEF 512
#define NSTK 256
#define CCO  128
#define SPIN 512
#define SPOUT 256
#define DNIN 128
#define DNOUT 128
#define NPNT 32
#define SP_ELEMS (NB * SPOUT * NBEF)   // 2,097,152 f32 elems (sparse output)

typedef __attribute__((ext_vector_type(8))) short bf16x8v;   // 8 bf16 = 4 VGPR
typedef __attribute__((ext_vector_type(4))) float f32x4v;    // MFMA C/D

__device__ __forceinline__ unsigned short f32_to_bf16(float f) {
    unsigned int u = __float_as_uint(f);
    u += 0x7fffu + ((u >> 16) & 1u);     // round-to-nearest-even
    return (unsigned short)(u >> 16);
}

__device__ __forceinline__ float gelu_tanh(float x) {
    float inner = 0.7978845608028654f * (x + 0.044715f * x * x * x);
    return 0.5f * x * (1.0f + tanhf(inner));
}

// order-preserving float -> uint map (handles possible tiny negative d2 exactly)
__device__ __forceinline__ unsigned int f2ord(float f) {
    unsigned int u = __float_as_uint(f);
    return (u & 0x80000000u) ? ~u : (u | 0x80000000u);
}
__device__ __forceinline__ float ord2f(unsigned int o) {
    unsigned int u = (o & 0x80000000u) ? (o & 0x7fffffffu) : ~o;
    return __uint_as_float(u);
}

// ---------------- Kernel 0: 2-NN + weights -> workspace (wave-parallel top-2) ----------------
__global__ __launch_bounds__(256) void knn_kernel(
    const float* __restrict__ stk_coor,      // [B][256][128]
    const float* __restrict__ stk_coor_bef,  // [B][512][128]
    int2* __restrict__ idx_out,              // [B][512]
    float2* __restrict__ w_out)              // [B][512]
{
    int n = blockIdx.x, b = blockIdx.y;
    int tid = threadIdx.x;                   // tid == stroke j

    __shared__ float bef[CCO];
    __shared__ unsigned long long wtop[8];   // 4 waves x top-2

    const float* befp = stk_coor_bef + ((size_t)b * NBEF + n) * CCO;
    if (tid < CCO) bef[tid] = befp[tid];
    __syncthreads();

    const float* sp = stk_coor + ((size_t)b * NSTK + tid) * CCO;
    float dot = 0.f, na = 0.f, nb = 0.f;
    #pragma unroll 8
    for (int c = 0; c < CCO; c += 4) {
        float4 s = *reinterpret_cast<const float4*>(sp + c);
        float b0 = bef[c], b1 = bef[c+1], b2 = bef[c+2], b3 = bef[c+3];
        dot += b0*s.x + b1*s.y + b2*s.z + b3*s.w;
        na  += b0*b0 + b1*b1 + b2*b2 + b3*b3;
        nb  += s.x*s.x + s.y*s.y + s.z*s.z + s.w*s.w;
    }
    float d2 = na + nb - 2.f * dot;

    // key: smaller d2 first; ties -> lower j (matches lax.top_k stable order)
    unsigned long long key = ((unsigned long long)f2ord(d2) << 32) | (unsigned int)tid;
    unsigned long long k1 = key;
    #pragma unroll
    for (int d = 32; d >= 1; d >>= 1) {
        unsigned long long o = __shfl_xor(k1, d, 64);
        if (o < k1) k1 = o;
    }
    unsigned long long kx = (key == k1) ? 0xFFFFFFFFFFFFFFFFull : key;
    unsigned long long k2 = kx;
    #pragma unroll
    for (int d = 32; d >= 1; d >>= 1) {
        unsigned long long o = __shfl_xor(k2, d, 64);
        if (o < k2) k2 = o;
    }
    if ((tid & 63) == 0) {
        wtop[(tid >> 6) * 2]     = k1;
        wtop[(tid >> 6) * 2 + 1] = k2;
    }
    __syncthreads();
    if (tid == 0) {
        unsigned long long m0 = 0xFFFFFFFFFFFFFFFFull, m1 = 0xFFFFFFFFFFFFFFFFull;
        #pragma unroll
        for (int i = 0; i < 8; ++i) {
            unsigned long long v = wtop[i];
            if (v < m0)      { m1 = m0; m0 = v; }
            else if (v < m1) { m1 = v; }
        }
        float d0 = ord2f((unsigned int)(m0 >> 32));
        float d1 = ord2f((unsigned int)(m1 >> 32));
        int j0 = (int)(m0 & 0xffffffffu), j1 = (int)(m1 & 0xffffffffu);
        float q0 = 1.f / (d0 + 1e-8f);
        float q1 = 1.f / (d1 + 1e-8f);
        float s = q0 + q1;
        idx_out[b * NBEF + n] = make_int2(j0, j1);
        w_out[b * NBEF + n]   = make_float2(q0 / s, q1 / s);
    }
}

// ---------------- Kernel 1: one-time A-matrix -> MFMA-fragment-linear bf16 ----------------
// A[m][k] (256x256): m<128: o=m, tap=(k<128?3:1); m>=128: o=m-128, tap=(k<128?2:0); i=k&127.
// Layout: [mt16(16)][ks(8)][lane(64)][j(8)] bf16, fragment elem (lane,j) = A[mt16*16+(lane&15)][ks*32+(lane>>4)*8+j]
__global__ __launch_bounds__(256) void prep_a_kernel(
    const float* __restrict__ w_ct,          // [128][128][4]
    unsigned short* __restrict__ Aws)        // 65536 bf16
{
    int g = blockIdx.x * 256 + threadIdx.x;  // 0..8191
    int lane = g & 63;
    int ks = (g >> 6) & 7;
    int mt16 = g >> 9;
    int m = mt16 * 16 + (lane & 15);
    int o = m & 127;
    int modd = (m >= 128);
    unsigned short t8[8];
    #pragma unroll
    for (int j = 0; j < 8; ++j) {
        int k = ks * 32 + (lane >> 4) * 8 + j;
        int i = k & 127;
        int tap = modd ? (k < 128 ? 2 : 0) : (k < 128 ? 3 : 1);
        t8[j] = f32_to_bf16(w_ct[((size_t)i * DNOUT + o) * 4 + tap]);
    }
    *reinterpret_cast<uint4*>(Aws + (size_t)g * 8) = *reinterpret_cast<const uint4*>(t8);
}

// ---------------- Kernel A: fused sparse branch (reads ws kNN) ----------------
__global__ __launch_bounds__(256) void sparse_direct_kernel(
    const float* __restrict__ SF,            // [16][512][256]
    const float* __restrict__ w_sp,          // [256][512]
    const int2* __restrict__ idxws, const float2* __restrict__ wgtws,
    const float* __restrict__ b_sp, const float* __restrict__ gamma_sp,
    const float* __restrict__ beta_sp,
    float* __restrict__ out)                 // [16][256][512] f32
{
    int b = blockIdx.y;
    int n0 = blockIdx.x * 8;                 // grid.x = 64
    int tid = threadIdx.x;

    __shared__ float fs[SPIN][8];            // 16 KB
    __shared__ int2   sij[8];
    __shared__ float2 swt[8];

    if (tid < 8) {
        sij[tid] = idxws[b * NBEF + n0 + tid];
        swt[tid] = wgtws[b * NBEF + n0 + tid];
    }
    __syncthreads();

    for (int l = tid; l < SPIN * 8; l += 256) {
        int c = l >> 3, nn = l & 7;
        int2  ij = sij[nn];
        float2 w = swt[nn];
        const float* row = SF + ((size_t)b * SPIN + c) * NSTK;
        fs[c][nn] = w.x * row[ij.x] + w.y * row[ij.y];
    }
    __syncthreads();

    int o = tid;
    float acc[8] = {0,0,0,0,0,0,0,0};
    const float4* wr4 = reinterpret_cast<const float4*>(w_sp + (size_t)o * SPIN);
    #pragma unroll 4
    for (int c4 = 0; c4 < SPIN / 4; ++c4) {
        float4 a = wr4[c4];
        int c = c4 * 4;
        #pragma unroll
        for (int nn = 0; nn < 8; ++nn)
            acc[nn] += a.x * fs[c][nn] + a.y * fs[c+1][nn]
                     + a.z * fs[c+2][nn] + a.w * fs[c+3][nn];
    }

    const float invs = 1.0f / sqrtf(1.0f + 1e-5f);
    float bias  = b_sp[o];
    float scale = gamma_sp[o] * invs;
    float beta  = beta_sp[o];
    float r[8];
    #pragma unroll
    for (int q = 0; q < 8; ++q)
        r[q] = gelu_tanh((acc[q] + bias) * scale + beta);
    float* dst = out + ((size_t)b * SPOUT + o) * NBEF + n0;
    *reinterpret_cast<float4*>(dst)     = make_float4(r[0], r[1], r[2], r[3]);
    *reinterpret_cast<float4*>(dst + 4) = make_float4(r[4], r[5], r[6], r[7]);
}

// ---------------- Kernel B: dense branch via bf16 MFMA (A preloaded from ws) ----------------
// C[m,c] = sum_k A[m,k]*B[k,c]; B[k<128][c]=xt[k][S0+c], B[k>=128][c]=xt[k-128][S0+c+1].
// Wave wid owns o-rows [wid*16,+16): mt=0 -> m=o (even taps), mt=1 -> m=o+128 (odd taps).
// y[o, 2c] = C[o, c] (c<128); y[o, 2c-1] = C[o+128, c] (1<=c<=128).
__global__ __launch_bounds__(512) void dense_mfma_kernel(
    const float* __restrict__ DF,            // [16][128][256][32]
    const unsigned short* __restrict__ Aws,  // fragment-linear A, 128 KB
    const float* __restrict__ b_ct,
    const float* __restrict__ gamma_dn,
    const float* __restrict__ beta_dn,
    const int2* __restrict__ idxws, const float2* __restrict__ wgtws,
    float* __restrict__ outd)                // [16][128][32768] f32 (already offset)
{
    int blk = blockIdx.x;                    // 0..127 (4 strokes each)
    int b   = blockIdx.y;
    int n0  = blk * 4;
    int S0  = n0 * 32;
    int T0  = n0 * 64;
    int tid  = threadIdx.x;
    int lane = tid & 63;
    int wid  = tid >> 6;                     // 0..7
    int rit  = lane & 15;
    int kgrp = lane >> 4;                    // 0..3

    __shared__ unsigned short Xs[146 * 128]; // 37376 B
    __shared__ int2   sij[6];
    __shared__ float2 swt[6];
    __shared__ float bnb[128], bns[128], bnt[128];

    const float invs = 1.0f / sqrtf(1.0f + 1e-5f);
    if (tid < 128) {
        bnb[tid] = b_ct[tid];
        bns[tid] = gamma_dn[tid] * invs;
        bnt[tid] = beta_dn[tid];
    }
    if (tid < 6) {
        int s = n0 - 1 + tid;
        s = (s < 0) ? 0 : ((s > NBEF - 1) ? NBEF - 1 : s);
        sij[tid] = idxws[b * NBEF + s];
        swt[tid] = wgtws[b * NBEF + s];
    }
    // zero-fill pad cols 130..145
    if (tid < 256) {
        uint4 z = make_uint4(0, 0, 0, 0);
        *reinterpret_cast<uint4*>(&Xs[130 * 128 + tid * 8]) = z;
    }
    __syncthreads();

    const float* DFb = DF + (size_t)b * (DNIN * NSTK * NPNT);

    // ---- stage core cols 1..128 (strokes n0..n0+3) ----
    {
        int sp = tid & 31, ig = tid >> 5;    // ig 0..15 -> i range ig*8..+8
        #pragma unroll
        for (int nl = 0; nl < 4; ++nl) {
            int2  ij = sij[nl + 1];
            float2 w = swt[nl + 1];
            const float* r0 = DFb + (size_t)ij.x * NPNT + sp;
            const float* r1 = DFb + (size_t)ij.y * NPNT + sp;
            int col = nl * 32 + sp + 1;
            unsigned short t8[8];
            #pragma unroll
            for (int p = 0; p < 8; ++p) {
                int i = ig * 8 + p;
                float v = w.x * r0[(size_t)i * 8192] + w.y * r1[(size_t)i * 8192];
                t8[p] = f32_to_bf16(v);
            }
            int dst = col * 128 + ((ig ^ (col & 15)) << 3);
            *reinterpret_cast<uint4*>(&Xs[dst]) = *reinterpret_cast<const uint4*>(t8);
        }
    }
    // ---- halo cols 0 and 129 ----
    if (tid < 256) {
        int i    = tid & 127;
        int side = tid >> 7;
        int col  = side ? 129 : 0;
        int L    = side ? (S0 + 128) : (S0 - 1);
        L = (L < 0) ? 0 : ((L > 16383) ? 16383 : L);
        int stroke = L >> 5, pt = L & 31;
        int slot = stroke - (n0 - 1);
        int2  ij = sij[slot];
        float2 w = swt[slot];
        float v = w.x * DFb[(size_t)i * 8192 + (size_t)ij.x * NPNT + pt]
                + w.y * DFb[(size_t)i * 8192 + (size_t)ij.y * NPNT + pt];
        int dst = col * 128 + ((((i >> 3) ^ (col & 15))) << 3) + (i & 7);
        Xs[dst] = f32_to_bf16(v);
    }

    // ---- A fragments: coalesced 16B loads from fragment-linear ws ----
    bf16x8v afrag[2][8];
    #pragma unroll
    for (int mt = 0; mt < 2; ++mt) {
        int mt16 = wid + mt * 8;
        #pragma unroll
        for (int ks = 0; ks < 8; ++ks) {
            afrag[mt][ks] = *reinterpret_cast<const bf16x8v*>(
                Aws + (((size_t)(mt16 * 8 + ks)) * 64 + lane) * 8);
        }
    }
    __syncthreads();

    // ---- MFMA main loop: 9 N-tiles x 8 K-steps x 2 M-tiles ----
    #pragma unroll 1
    for (int nt = 0; nt < 9; ++nt) {
        f32x4v acc0 = {0.f, 0.f, 0.f, 0.f};
        f32x4v acc1 = {0.f, 0.f, 0.f, 0.f};
        #pragma unroll
        for (int ks = 0; ks < 8; ++ks) {
            int kb   = ks * 32 + kgrp * 8;
            int half = kb >> 7;              // 0: k<128 (col c), 1: k>=128 (col c+1)
            int i    = kb & 127;
            int col  = nt * 16 + rit + half;
            int src  = col * 128 + ((((i >> 3) ^ (col & 15))) << 3);
            bf16x8v bfrag = *reinterpret_cast<const bf16x8v*>(&Xs[src]);
            acc0 = __builtin_amdgcn_mfma_f32_16x16x32_bf16(afrag[0][ks], bfrag, acc0, 0, 0, 0);
            acc1 = __builtin_amdgcn_mfma_f32_16x16x32_bf16(afrag[1][ks], bfrag, acc1, 0, 0, 0);
        }
        int c = nt * 16 + rit;               // C/D col = lane&15
        if (c <= 128) {
            #pragma unroll
            for (int q = 0; q < 4; ++q) {
                int o = wid * 16 + kgrp * 4 + q;   // C/D row = (lane>>4)*4+q
                size_t rowbase = (((size_t)b * DNOUT + o) << 15) + (size_t)T0;
                float bias = bnb[o], scale = bns[o], beta = bnt[o];
                if (c < 128) {
                    float ye = gelu_tanh((acc0[q] + bias) * scale + beta);
                    outd[rowbase + 2 * c] = ye;            // even t
                }
                if (c >= 1) {
                    float yo = gelu_tanh((acc1[q] + bias) * scale + beta);
                    outd[rowbase + 2 * c - 1] = yo;        // odd t
                }
            }
        }
    }
}

extern "C" void kernel_launch(void* const* d_in, const int* in_sizes, int n_in,
                              void* d_out, int out_size, void* d_ws, size_t ws_size,
                              hipStream_t stream) {
    const float* sparse_fea   = (const float*)d_in[0];
    const float* dense_fea    = (const float*)d_in[1];
    const float* stk_coor     = (const float*)d_in[2];
    const float* stk_coor_bef = (const float*)d_in[3];
    const float* w_sp     = (const float*)d_in[4];
    const float* b_sp     = (const float*)d_in[5];
    const float* gamma_sp = (const float*)d_in[6];
    const float* beta_sp  = (const float*)d_in[7];
    const float* w_ct     = (const float*)d_in[8];
    const float* b_ct     = (const float*)d_in[9];
    const float* gamma_dn = (const float*)d_in[10];
    const float* beta_dn  = (const float*)d_in[11];
    float* out = (float*)d_out;

    char* ws = (char*)d_ws;
    int2*   idx = (int2*)ws;                          // 64 KB
    float2* wgt = (float2*)(ws + 65536);              // 64 KB
    unsigned short* Aws = (unsigned short*)(ws + 131072);  // 128 KB (total 256 KB)

    knn_kernel<<<dim3(NBEF, NB), 256, 0, stream>>>(stk_coor, stk_coor_bef, idx, wgt);
    prep_a_kernel<<<32, 256, 0, stream>>>(w_ct, Aws);
    sparse_direct_kernel<<<dim3(NBEF / 8, NB), 256, 0, stream>>>(
        sparse_fea, w_sp, idx, wgt, b_sp, gamma_sp, beta_sp, out);
    dense_mfma_kernel<<<dim3(NBEF / 4, NB), 512, 0, stream>>>(
        dense_fea, Aws, b_ct, gamma_dn, beta_dn, idx, wgt, out + SP_ELEMS);
}

// Round 8
// 240.983 us; speedup vs baseline: 5.0549x; 1.7173x over previous
//
#include <hip/hip_runtime.h>
#include <math.h>

#define NB   16
#define NBEF 512
#define NSTK 256
#define CCO  128
#define SPIN 512
#define SPOUT 256
#define DNIN 128
#define DNOUT 128
#define NPNT 32
#define SP_ELEMS (NB * SPOUT * NBEF)   // 2,097,152 f32 elems (sparse output)

typedef __attribute__((ext_vector_type(8))) short bf16x8v;   // 8 bf16 = 4 VGPR
typedef __attribute__((ext_vector_type(4))) float f32x4v;    // MFMA C/D

__device__ __forceinline__ unsigned short f32_to_bf16(float f) {
    unsigned int u = __float_as_uint(f);
    u += 0x7fffu + ((u >> 16) & 1u);     // round-to-nearest-even
    return (unsigned short)(u >> 16);
}

__device__ __forceinline__ float gelu_tanh(float x) {
    float inner = 0.7978845608028654f * (x + 0.044715f * x * x * x);
    return 0.5f * x * (1.0f + tanhf(inner));
}

// order-preserving float -> uint map
__device__ __forceinline__ unsigned int f2ord(float f) {
    unsigned int u = __float_as_uint(f);
    return (u & 0x80000000u) ? ~u : (u | 0x80000000u);
}
__device__ __forceinline__ float ord2f(unsigned int o) {
    unsigned int u = (o & 0x80000000u) ? (o & 0x7fffffffu) : ~o;
    return __uint_as_float(u);
}

__device__ __forceinline__ unsigned long long wave_min_u64(unsigned long long k) {
    #pragma unroll
    for (int d = 32; d >= 1; d >>= 1) {
        unsigned long long o = __shfl_xor(k, d, 64);
        if (o < k) k = o;
    }
    return k;
}

// ---------------- Kernel 0: tiled 2-NN (GEMM-style staging, wave-local top-2) ----------------
// Block: (b, 16 queries). Wave qg owns queries qg*4..+4 x ALL 256 points (4 per lane).
__global__ __launch_bounds__(256) void knn_kernel(
    const float* __restrict__ stk_coor,      // [B][256][128]
    const float* __restrict__ stk_coor_bef,  // [B][512][128]
    int2* __restrict__ idx_out,              // [B][512]
    float2* __restrict__ w_out)              // [B][512]
{
    int b  = blockIdx.y;
    int q0 = blockIdx.x * 16;
    int tid  = threadIdx.x;
    int lane = tid & 63;
    int qg   = tid >> 6;                     // wave id: queries qg*4..+4
    int pg   = lane;                         // points pg*4..+4

    __shared__ float Qt[128][16];            // [c][q] 8 KB
    __shared__ float Pt[32][260];            // [c-chunk][p] 33.3 KB (pad 4)

    // stage Qt transposed (coalesced global, one-time)
    {
        int q = tid >> 4, c0 = (tid & 15) * 8;
        const float* src = stk_coor_bef + ((size_t)b * NBEF + q0 + q) * CCO + c0;
        float4 v0 = *reinterpret_cast<const float4*>(src);
        float4 v1 = *reinterpret_cast<const float4*>(src + 4);
        Qt[c0+0][q] = v0.x; Qt[c0+1][q] = v0.y; Qt[c0+2][q] = v0.z; Qt[c0+3][q] = v0.w;
        Qt[c0+4][q] = v1.x; Qt[c0+5][q] = v1.y; Qt[c0+6][q] = v1.z; Qt[c0+7][q] = v1.w;
    }

    float dot[4][4];
    #pragma unroll
    for (int a = 0; a < 4; ++a)
        #pragma unroll
        for (int c = 0; c < 4; ++c) dot[a][c] = 0.f;
    float qn[4] = {0.f, 0.f, 0.f, 0.f};
    float pn[4] = {0.f, 0.f, 0.f, 0.f};

    for (int ct = 0; ct < 4; ++ct) {
        __syncthreads();                     // protect previous chunk (also covers Qt on ct=0)
        // stage c-chunk of P: [ct*32, +32) x 256 points, coalesced 128B granules
        #pragma unroll
        for (int it = 0; it < 8; ++it) {
            int p  = (tid >> 3) + it * 32;
            int cl = (tid & 7) * 4;
            float4 v = *reinterpret_cast<const float4*>(
                stk_coor + ((size_t)b * NSTK + p) * CCO + ct * 32 + cl);
            Pt[cl+0][p] = v.x; Pt[cl+1][p] = v.y; Pt[cl+2][p] = v.z; Pt[cl+3][p] = v.w;
        }
        __syncthreads();
        #pragma unroll 8
        for (int c = 0; c < 32; ++c) {
            float4 qv = *reinterpret_cast<const float4*>(&Qt[ct*32 + c][qg*4]);
            float4 pv = *reinterpret_cast<const float4*>(&Pt[c][pg*4]);
            float qa[4] = {qv.x, qv.y, qv.z, qv.w};
            float pa[4] = {pv.x, pv.y, pv.z, pv.w};
            #pragma unroll
            for (int j = 0; j < 4; ++j) {
                qn[j] += qa[j] * qa[j];
                pn[j] += pa[j] * pa[j];
                #pragma unroll
                for (int k = 0; k < 4; ++k) dot[j][k] += qa[j] * pa[k];
            }
        }
    }

    // per-query top-2, entirely within the wave (covers all 256 points)
    #pragma unroll
    for (int qj = 0; qj < 4; ++qj) {
        unsigned long long kA = 0xFFFFFFFFFFFFFFFFull, kB = 0xFFFFFFFFFFFFFFFFull;
        #pragma unroll
        for (int pj = 0; pj < 4; ++pj) {
            float d2 = qn[qj] + pn[pj] - 2.f * dot[qj][pj];
            unsigned long long key =
                ((unsigned long long)f2ord(d2) << 32) | (unsigned int)(pg * 4 + pj);
            if (key < kA)      { kB = kA; kA = key; }
            else if (key < kB) { kB = key; }
        }
        unsigned long long m0 = wave_min_u64(kA);
        unsigned long long c2 = (kA == m0) ? kB : kA;
        unsigned long long m1 = wave_min_u64(c2);
        if (lane == 0) {
            float d0 = ord2f((unsigned int)(m0 >> 32));
            float d1 = ord2f((unsigned int)(m1 >> 32));
            int j0 = (int)(m0 & 0xffffffffu), j1 = (int)(m1 & 0xffffffffu);
            float r0 = 1.f / (d0 + 1e-8f);
            float r1 = 1.f / (d1 + 1e-8f);
            float s = r0 + r1;
            int q = q0 + qg * 4 + qj;
            idx_out[b * NBEF + q] = make_int2(j0, j1);
            w_out[b * NBEF + q]   = make_float2(r0 / s, r1 / s);
        }
    }
}

// ---------------- Kernel 1: one-time A-matrix -> MFMA-fragment-linear bf16 ----------------
__global__ __launch_bounds__(256) void prep_a_kernel(
    const float* __restrict__ w_ct,          // [128][128][4]
    unsigned short* __restrict__ Aws)        // 65536 bf16
{
    int g = blockIdx.x * 256 + threadIdx.x;  // 0..8191
    int lane = g & 63;
    int ks = (g >> 6) & 7;
    int mt16 = g >> 9;
    int m = mt16 * 16 + (lane & 15);
    int o = m & 127;
    int modd = (m >= 128);
    unsigned short t8[8];
    #pragma unroll
    for (int j = 0; j < 8; ++j) {
        int k = ks * 32 + (lane >> 4) * 8 + j;
        int i = k & 127;
        int tap = modd ? (k < 128 ? 2 : 0) : (k < 128 ? 3 : 1);
        t8[j] = f32_to_bf16(w_ct[((size_t)i * DNOUT + o) * 4 + tap]);
    }
    *reinterpret_cast<uint4*>(Aws + (size_t)g * 8) = *reinterpret_cast<const uint4*>(t8);
}

// ---------------- Kernel A: fused sparse branch (reads ws kNN) ----------------
__global__ __launch_bounds__(256) void sparse_direct_kernel(
    const float* __restrict__ SF,            // [16][512][256]
    const float* __restrict__ w_sp,          // [256][512]
    const int2* __restrict__ idxws, const float2* __restrict__ wgtws,
    const float* __restrict__ b_sp, const float* __restrict__ gamma_sp,
    const float* __restrict__ beta_sp,
    float* __restrict__ out)                 // [16][256][512] f32
{
    int b = blockIdx.y;
    int n0 = blockIdx.x * 8;                 // grid.x = 64
    int tid = threadIdx.x;

    __shared__ float fs[SPIN][8];            // 16 KB
    __shared__ int2   sij[8];
    __shared__ float2 swt[8];

    if (tid < 8) {
        sij[tid] = idxws[b * NBEF + n0 + tid];
        swt[tid] = wgtws[b * NBEF + n0 + tid];
    }
    __syncthreads();

    for (int l = tid; l < SPIN * 8; l += 256) {
        int c = l >> 3, nn = l & 7;
        int2  ij = sij[nn];
        float2 w = swt[nn];
        const float* row = SF + ((size_t)b * SPIN + c) * NSTK;
        fs[c][nn] = w.x * row[ij.x] + w.y * row[ij.y];
    }
    __syncthreads();

    int o = tid;
    float acc[8] = {0,0,0,0,0,0,0,0};
    const float4* wr4 = reinterpret_cast<const float4*>(w_sp + (size_t)o * SPIN);
    #pragma unroll 4
    for (int c4 = 0; c4 < SPIN / 4; ++c4) {
        float4 a = wr4[c4];
        int c = c4 * 4;
        #pragma unroll
        for (int nn = 0; nn < 8; ++nn)
            acc[nn] += a.x * fs[c][nn] + a.y * fs[c+1][nn]
                     + a.z * fs[c+2][nn] + a.w * fs[c+3][nn];
    }

    const float invs = 1.0f / sqrtf(1.0f + 1e-5f);
    float bias  = b_sp[o];
    float scale = gamma_sp[o] * invs;
    float beta  = beta_sp[o];
    float r[8];
    #pragma unroll
    for (int q = 0; q < 8; ++q)
        r[q] = gelu_tanh((acc[q] + bias) * scale + beta);
    float* dst = out + ((size_t)b * SPOUT + o) * NBEF + n0;
    *reinterpret_cast<float4*>(dst)     = make_float4(r[0], r[1], r[2], r[3]);
    *reinterpret_cast<float4*>(dst + 4) = make_float4(r[4], r[5], r[6], r[7]);
}

// ---------------- Kernel B: dense branch via bf16 MFMA (A preloaded from ws) ----------------
__global__ __launch_bounds__(512) void dense_mfma_kernel(
    const float* __restrict__ DF,            // [16][128][256][32]
    const unsigned short* __restrict__ Aws,  // fragment-linear A, 128 KB
    const float* __restrict__ b_ct,
    const float* __restrict__ gamma_dn,
    const float* __restrict__ beta_dn,
    const int2* __restrict__ idxws, const float2* __restrict__ wgtws,
    float* __restrict__ outd)                // [16][128][32768] f32 (already offset)
{
    int blk = blockIdx.x;                    // 0..127 (4 strokes each)
    int b   = blockIdx.y;
    int n0  = blk * 4;
    int S0  = n0 * 32;
    int T0  = n0 * 64;
    int tid  = threadIdx.x;
    int lane = tid & 63;
    int wid  = tid >> 6;                     // 0..7
    int rit  = lane & 15;
    int kgrp = lane >> 4;                    // 0..3

    __shared__ unsigned short Xs[146 * 128]; // 37376 B
    __shared__ int2   sij[6];
    __shared__ float2 swt[6];
    __shared__ float bnb[128], bns[128], bnt[128];

    const float invs = 1.0f / sqrtf(1.0f + 1e-5f);
    if (tid < 128) {
        bnb[tid] = b_ct[tid];
        bns[tid] = gamma_dn[tid] * invs;
        bnt[tid] = beta_dn[tid];
    }
    if (tid < 6) {
        int s = n0 - 1 + tid;
        s = (s < 0) ? 0 : ((s > NBEF - 1) ? NBEF - 1 : s);
        sij[tid] = idxws[b * NBEF + s];
        swt[tid] = wgtws[b * NBEF + s];
    }
    if (tid < 256) {
        uint4 z = make_uint4(0, 0, 0, 0);
        *reinterpret_cast<uint4*>(&Xs[130 * 128 + tid * 8]) = z;
    }
    __syncthreads();

    const float* DFb = DF + (size_t)b * (DNIN * NSTK * NPNT);

    // ---- stage core cols 1..128 (strokes n0..n0+3) ----
    {
        int sp = tid & 31, ig = tid >> 5;    // ig 0..15 -> i range ig*8..+8
        #pragma unroll
        for (int nl = 0; nl < 4; ++nl) {
            int2  ij = sij[nl + 1];
            float2 w = swt[nl + 1];
            const float* r0 = DFb + (size_t)ij.x * NPNT + sp;
            const float* r1 = DFb + (size_t)ij.y * NPNT + sp;
            int col = nl * 32 + sp + 1;
            unsigned short t8[8];
            #pragma unroll
            for (int p = 0; p < 8; ++p) {
                int i = ig * 8 + p;
                float v = w.x * r0[(size_t)i * 8192] + w.y * r1[(size_t)i * 8192];
                t8[p] = f32_to_bf16(v);
            }
            int dst = col * 128 + ((ig ^ (col & 15)) << 3);
            *reinterpret_cast<uint4*>(&Xs[dst]) = *reinterpret_cast<const uint4*>(t8);
        }
    }
    // ---- halo cols 0 and 129 ----
    if (tid < 256) {
        int i    = tid & 127;
        int side = tid >> 7;
        int col  = side ? 129 : 0;
        int L    = side ? (S0 + 128) : (S0 - 1);
        L = (L < 0) ? 0 : ((L > 16383) ? 16383 : L);
        int stroke = L >> 5, pt = L & 31;
        int slot = stroke - (n0 - 1);
        int2  ij = sij[slot];
        float2 w = swt[slot];
        float v = w.x * DFb[(size_t)i * 8192 + (size_t)ij.x * NPNT + pt]
                + w.y * DFb[(size_t)i * 8192 + (size_t)ij.y * NPNT + pt];
        int dst = col * 128 + ((((i >> 3) ^ (col & 15))) << 3) + (i & 7);
        Xs[dst] = f32_to_bf16(v);
    }

    // ---- A fragments: coalesced 16B loads from fragment-linear ws ----
    bf16x8v afrag[2][8];
    #pragma unroll
    for (int mt = 0; mt < 2; ++mt) {
        int mt16 = wid + mt * 8;
        #pragma unroll
        for (int ks = 0; ks < 8; ++ks) {
            afrag[mt][ks] = *reinterpret_cast<const bf16x8v*>(
                Aws + (((size_t)(mt16 * 8 + ks)) * 64 + lane) * 8);
        }
    }
    __syncthreads();

    // ---- MFMA main loop: 9 N-tiles x 8 K-steps x 2 M-tiles ----
    #pragma unroll 1
    for (int nt = 0; nt < 9; ++nt) {
        f32x4v acc0 = {0.f, 0.f, 0.f, 0.f};
        f32x4v acc1 = {0.f, 0.f, 0.f, 0.f};
        #pragma unroll
        for (int ks = 0; ks < 8; ++ks) {
            int kb   = ks * 32 + kgrp * 8;
            int half = kb >> 7;
            int i    = kb & 127;
            int col  = nt * 16 + rit + half;
            int src  = col * 128 + ((((i >> 3) ^ (col & 15))) << 3);
            bf16x8v bfrag = *reinterpret_cast<const bf16x8v*>(&Xs[src]);
            acc0 = __builtin_amdgcn_mfma_f32_16x16x32_bf16(afrag[0][ks], bfrag, acc0, 0, 0, 0);
            acc1 = __builtin_amdgcn_mfma_f32_16x16x32_bf16(afrag[1][ks], bfrag, acc1, 0, 0, 0);
        }
        int c = nt * 16 + rit;
        if (c <= 128) {
            #pragma unroll
            for (int q = 0; q < 4; ++q) {
                int o = wid * 16 + kgrp * 4 + q;
                size_t rowbase = (((size_t)b * DNOUT + o) << 15) + (size_t)T0;
                float bias = bnb[o], scale = bns[o], beta = bnt[o];
                if (c < 128) {
                    float ye = gelu_tanh((acc0[q] + bias) * scale + beta);
                    outd[rowbase + 2 * c] = ye;
                }
                if (c >= 1) {
                    float yo = gelu_tanh((acc1[q] + bias) * scale + beta);
                    outd[rowbase + 2 * c - 1] = yo;
                }
            }
        }
    }
}

extern "C" void kernel_launch(void* const* d_in, const int* in_sizes, int n_in,
                              void* d_out, int out_size, void* d_ws, size_t ws_size,
                              hipStream_t stream) {
    const float* sparse_fea   = (const float*)d_in[0];
    const float* dense_fea    = (const float*)d_in[1];
    const float* stk_coor     = (const float*)d_in[2];
    const float* stk_coor_bef = (const float*)d_in[3];
    const float* w_sp     = (const float*)d_in[4];
    const float* b_sp     = (const float*)d_in[5];
    const float* gamma_sp = (const float*)d_in[6];
    const float* beta_sp  = (const float*)d_in[7];
    const float* w_ct     = (const float*)d_in[8];
    const float* b_ct     = (const float*)d_in[9];
    const float* gamma_dn = (const float*)d_in[10];
    const float* beta_dn  = (const float*)d_in[11];
    float* out = (float*)d_out;

    char* ws = (char*)d_ws;
    int2*   idx = (int2*)ws;                          // 64 KB
    float2* wgt = (float2*)(ws + 65536);              // 64 KB
    unsigned short* Aws = (unsigned short*)(ws + 131072);  // 128 KB (total 256 KB)

    knn_kernel<<<dim3(NBEF / 16, NB), 256, 0, stream>>>(stk_coor, stk_coor_bef, idx, wgt);
    prep_a_kernel<<<32, 256, 0, stream>>>(w_ct, Aws);
    sparse_direct_kernel<<<dim3(NBEF / 8, NB), 256, 0, stream>>>(
        sparse_fea, w_sp, idx, wgt, b_sp, gamma_sp, beta_sp, out);
    dense_mfma_kernel<<<dim3(NBEF / 4, NB), 512, 0, stream>>>(
        dense_fea, Aws, b_ct, gamma_dn, beta_dn, idx, wgt, out + SP_ELEMS);
}

// Round 9
// 228.283 us; speedup vs baseline: 5.3361x; 1.0556x over previous
//
#include <hip/hip_runtime.h>
#include <math.h>

#define NB   16
#define NBEF 512
#define NSTK 256
#define CCO  128
#define SPIN 512
#define SPOUT 256
#define DNIN 128
#define DNOUT 128
#define NPNT 32
#define SP_ELEMS (NB * SPOUT * NBEF)   // 2,097,152 f32 elems (sparse output)

typedef __attribute__((ext_vector_type(8))) short bf16x8v;   // 8 bf16 = 4 VGPR
typedef __attribute__((ext_vector_type(4))) float f32x4v;    // MFMA C/D

__device__ __forceinline__ unsigned short f32_to_bf16(float f) {
    unsigned int u = __float_as_uint(f);
    u += 0x7fffu + ((u >> 16) & 1u);     // round-to-nearest-even
    return (unsigned short)(u >> 16);
}

// gelu(tanh approx) with hw exp2: tanh(z)=sign(z)*(1-2/(2^(2|z|*log2e)+1))
__device__ __forceinline__ float fast_gelu(float x) {
    float z = 0.7978845608028654f * x * (1.0f + 0.044715f * x * x);
    float az = fabsf(z) * 2.885390081777927f;   // 2*log2(e)
    float e;
    asm("v_exp_f32 %0, %1" : "=v"(e) : "v"(az));
    float r = __builtin_amdgcn_rcpf(e + 1.0f);
    float th = copysignf(1.0f - 2.0f * r, z);
    return 0.5f * x * (1.0f + th);
}

// order-preserving float -> uint map
__device__ __forceinline__ unsigned int f2ord(float f) {
    unsigned int u = __float_as_uint(f);
    return (u & 0x80000000u) ? ~u : (u | 0x80000000u);
}
__device__ __forceinline__ float ord2f(unsigned int o) {
    unsigned int u = (o & 0x80000000u) ? (o & 0x7fffffffu) : ~o;
    return __uint_as_float(u);
}

__device__ __forceinline__ unsigned long long wave_min_u64(unsigned long long k) {
    #pragma unroll
    for (int d = 32; d >= 1; d >>= 1) {
        unsigned long long o = __shfl_xor(k, d, 64);
        if (o < k) k = o;
    }
    return k;
}

// ---------------- Kernel 0: tiled 2-NN (GEMM-style staging, wave-local top-2) ----------------
__global__ __launch_bounds__(256) void knn_kernel(
    const float* __restrict__ stk_coor,      // [B][256][128]
    const float* __restrict__ stk_coor_bef,  // [B][512][128]
    int2* __restrict__ idx_out,              // [B][512]
    float2* __restrict__ w_out)              // [B][512]
{
    int b  = blockIdx.y;
    int q0 = blockIdx.x * 16;
    int tid  = threadIdx.x;
    int lane = tid & 63;
    int qg   = tid >> 6;                     // wave id: queries qg*4..+4
    int pg   = lane;                         // points pg*4..+4

    __shared__ float Qt[128][16];            // [c][q] 8 KB
    __shared__ float Pt[32][260];            // [c-chunk][p] 33.3 KB (pad 4)

    {
        int q = tid >> 4, c0 = (tid & 15) * 8;
        const float* src = stk_coor_bef + ((size_t)b * NBEF + q0 + q) * CCO + c0;
        float4 v0 = *reinterpret_cast<const float4*>(src);
        float4 v1 = *reinterpret_cast<const float4*>(src + 4);
        Qt[c0+0][q] = v0.x; Qt[c0+1][q] = v0.y; Qt[c0+2][q] = v0.z; Qt[c0+3][q] = v0.w;
        Qt[c0+4][q] = v1.x; Qt[c0+5][q] = v1.y; Qt[c0+6][q] = v1.z; Qt[c0+7][q] = v1.w;
    }

    float dot[4][4];
    #pragma unroll
    for (int a = 0; a < 4; ++a)
        #pragma unroll
        for (int c = 0; c < 4; ++c) dot[a][c] = 0.f;
    float qn[4] = {0.f, 0.f, 0.f, 0.f};
    float pn[4] = {0.f, 0.f, 0.f, 0.f};

    for (int ct = 0; ct < 4; ++ct) {
        __syncthreads();
        #pragma unroll
        for (int it = 0; it < 8; ++it) {
            int p  = (tid >> 3) + it * 32;
            int cl = (tid & 7) * 4;
            float4 v = *reinterpret_cast<const float4*>(
                stk_coor + ((size_t)b * NSTK + p) * CCO + ct * 32 + cl);
            Pt[cl+0][p] = v.x; Pt[cl+1][p] = v.y; Pt[cl+2][p] = v.z; Pt[cl+3][p] = v.w;
        }
        __syncthreads();
        #pragma unroll 8
        for (int c = 0; c < 32; ++c) {
            float4 qv = *reinterpret_cast<const float4*>(&Qt[ct*32 + c][qg*4]);
            float4 pv = *reinterpret_cast<const float4*>(&Pt[c][pg*4]);
            float qa[4] = {qv.x, qv.y, qv.z, qv.w};
            float pa[4] = {pv.x, pv.y, pv.z, pv.w};
            #pragma unroll
            for (int j = 0; j < 4; ++j) {
                qn[j] += qa[j] * qa[j];
                pn[j] += pa[j] * pa[j];
                #pragma unroll
                for (int k = 0; k < 4; ++k) dot[j][k] += qa[j] * pa[k];
            }
        }
    }

    #pragma unroll
    for (int qj = 0; qj < 4; ++qj) {
        unsigned long long kA = 0xFFFFFFFFFFFFFFFFull, kB = 0xFFFFFFFFFFFFFFFFull;
        #pragma unroll
        for (int pj = 0; pj < 4; ++pj) {
            float d2 = qn[qj] + pn[pj] - 2.f * dot[qj][pj];
            unsigned long long key =
                ((unsigned long long)f2ord(d2) << 32) | (unsigned int)(pg * 4 + pj);
            if (key < kA)      { kB = kA; kA = key; }
            else if (key < kB) { kB = key; }
        }
        unsigned long long m0 = wave_min_u64(kA);
        unsigned long long c2 = (kA == m0) ? kB : kA;
        unsigned long long m1 = wave_min_u64(c2);
        if (lane == 0) {
            float d0 = ord2f((unsigned int)(m0 >> 32));
            float d1 = ord2f((unsigned int)(m1 >> 32));
            int j0 = (int)(m0 & 0xffffffffu), j1 = (int)(m1 & 0xffffffffu);
            float r0 = 1.f / (d0 + 1e-8f);
            float r1 = 1.f / (d1 + 1e-8f);
            float s = r0 + r1;
            int q = q0 + qg * 4 + qj;
            idx_out[b * NBEF + q] = make_int2(j0, j1);
            w_out[b * NBEF + q]   = make_float2(r0 / s, r1 / s);
        }
    }
}

// ---------------- Kernel 1: one-time A-matrix -> MFMA-fragment-linear bf16 ----------------
__global__ __launch_bounds__(256) void prep_a_kernel(
    const float* __restrict__ w_ct,          // [128][128][4]
    unsigned short* __restrict__ Aws)        // 65536 bf16
{
    int g = blockIdx.x * 256 + threadIdx.x;  // 0..8191
    int lane = g & 63;
    int ks = (g >> 6) & 7;
    int mt16 = g >> 9;
    int m = mt16 * 16 + (lane & 15);
    int o = m & 127;
    int modd = (m >= 128);
    unsigned short t8[8];
    #pragma unroll
    for (int j = 0; j < 8; ++j) {
        int k = ks * 32 + (lane >> 4) * 8 + j;
        int i = k & 127;
        int tap = modd ? (k < 128 ? 2 : 0) : (k < 128 ? 3 : 1);
        t8[j] = f32_to_bf16(w_ct[((size_t)i * DNOUT + o) * 4 + tap]);
    }
    *reinterpret_cast<uint4*>(Aws + (size_t)g * 8) = *reinterpret_cast<const uint4*>(t8);
}

// ---------------- Kernel A: fused sparse branch (reads ws kNN) ----------------
__global__ __launch_bounds__(256) void sparse_direct_kernel(
    const float* __restrict__ SF,            // [16][512][256]
    const float* __restrict__ w_sp,          // [256][512]
    const int2* __restrict__ idxws, const float2* __restrict__ wgtws,
    const float* __restrict__ b_sp, const float* __restrict__ gamma_sp,
    const float* __restrict__ beta_sp,
    float* __restrict__ out)                 // [16][256][512] f32
{
    int b = blockIdx.y;
    int n0 = blockIdx.x * 8;                 // grid.x = 64
    int tid = threadIdx.x;

    __shared__ float fs[SPIN][8];            // 16 KB
    __shared__ int2   sij[8];
    __shared__ float2 swt[8];

    if (tid < 8) {
        sij[tid] = idxws[b * NBEF + n0 + tid];
        swt[tid] = wgtws[b * NBEF + n0 + tid];
    }
    __syncthreads();

    for (int l = tid; l < SPIN * 8; l += 256) {
        int c = l >> 3, nn = l & 7;
        int2  ij = sij[nn];
        float2 w = swt[nn];
        const float* row = SF + ((size_t)b * SPIN + c) * NSTK;
        fs[c][nn] = w.x * row[ij.x] + w.y * row[ij.y];
    }
    __syncthreads();

    int o = tid;
    float acc[8] = {0,0,0,0,0,0,0,0};
    const float4* wr4 = reinterpret_cast<const float4*>(w_sp + (size_t)o * SPIN);
    #pragma unroll 4
    for (int c4 = 0; c4 < SPIN / 4; ++c4) {
        float4 a = wr4[c4];
        int c = c4 * 4;
        #pragma unroll
        for (int nn = 0; nn < 8; ++nn)
            acc[nn] += a.x * fs[c][nn] + a.y * fs[c+1][nn]
                     + a.z * fs[c+2][nn] + a.w * fs[c+3][nn];
    }

    const float invs = 1.0f / sqrtf(1.0f + 1e-5f);
    float bias  = b_sp[o];
    float scale = gamma_sp[o] * invs;
    float beta  = beta_sp[o];
    float r[8];
    #pragma unroll
    for (int q = 0; q < 8; ++q)
        r[q] = fast_gelu((acc[q] + bias) * scale + beta);
    float* dst = out + ((size_t)b * SPOUT + o) * NBEF + n0;
    *reinterpret_cast<float4*>(dst)     = make_float4(r[0], r[1], r[2], r[3]);
    *reinterpret_cast<float4*>(dst + 4) = make_float4(r[4], r[5], r[6], r[7]);
}

// ---------------- Kernel B: dense branch via bf16 MFMA (A preloaded from ws) ----------------
// C[m,c]: m<128 (even taps W3/W1), m>=128 (odd taps W2/W0); B[k<128][c]=xt[k][S0+c],
// B[k>=128][c]=xt[k-128][S0+c+1].  y[o,2c]=C[o,c] (c<128); y[o,2c-1]=C[o+128,c] (1<=c<=128).
// Epilogue pairing: lane rit gets C[o+128,c+1] (odd y@2c+1) from lane rit+1 via shfl ->
// aligned float2 {y@2c, y@2c+1}; lane rit==0 scalar-stores its own odd y@2c-1 (seams + t=255).
__global__ __launch_bounds__(512) void dense_mfma_kernel(
    const float* __restrict__ DF,            // [16][128][256][32]
    const unsigned short* __restrict__ Aws,  // fragment-linear A, 128 KB
    const float* __restrict__ b_ct,
    const float* __restrict__ gamma_dn,
    const float* __restrict__ beta_dn,
    const int2* __restrict__ idxws, const float2* __restrict__ wgtws,
    float* __restrict__ outd)                // [16][128][32768] f32 (already offset)
{
    int blk = blockIdx.x;                    // 0..127 (4 strokes each)
    int b   = blockIdx.y;
    int n0  = blk * 4;
    int S0  = n0 * 32;
    int T0  = n0 * 64;
    int tid  = threadIdx.x;
    int lane = tid & 63;
    int wid  = tid >> 6;                     // 0..7
    int rit  = lane & 15;
    int kgrp = lane >> 4;                    // 0..3

    __shared__ unsigned short Xs[146 * 128]; // 37376 B
    __shared__ int2   sij[6];
    __shared__ float2 swt[6];
    __shared__ float bnb[128], bns[128], bnt[128];

    const float invs = 1.0f / sqrtf(1.0f + 1e-5f);
    if (tid < 128) {
        bnb[tid] = b_ct[tid];
        bns[tid] = gamma_dn[tid] * invs;
        bnt[tid] = beta_dn[tid];
    }
    if (tid < 6) {
        int s = n0 - 1 + tid;
        s = (s < 0) ? 0 : ((s > NBEF - 1) ? NBEF - 1 : s);
        sij[tid] = idxws[b * NBEF + s];
        swt[tid] = wgtws[b * NBEF + s];
    }
    if (tid < 256) {
        uint4 z = make_uint4(0, 0, 0, 0);
        *reinterpret_cast<uint4*>(&Xs[130 * 128 + tid * 8]) = z;
    }
    __syncthreads();

    const float* DFb = DF + (size_t)b * (DNIN * NSTK * NPNT);

    // ---- stage core cols 1..128 (strokes n0..n0+3) ----
    {
        int sp = tid & 31, ig = tid >> 5;    // ig 0..15 -> i range ig*8..+8
        #pragma unroll
        for (int nl = 0; nl < 4; ++nl) {
            int2  ij = sij[nl + 1];
            float2 w = swt[nl + 1];
            const float* r0 = DFb + (size_t)ij.x * NPNT + sp;
            const float* r1 = DFb + (size_t)ij.y * NPNT + sp;
            int col = nl * 32 + sp + 1;
            unsigned short t8[8];
            #pragma unroll
            for (int p = 0; p < 8; ++p) {
                int i = ig * 8 + p;
                float v = w.x * r0[(size_t)i * 8192] + w.y * r1[(size_t)i * 8192];
                t8[p] = f32_to_bf16(v);
            }
            int dst = col * 128 + ((ig ^ (col & 15)) << 3);
            *reinterpret_cast<uint4*>(&Xs[dst]) = *reinterpret_cast<const uint4*>(t8);
        }
    }
    // ---- halo cols 0 and 129 ----
    if (tid < 256) {
        int i    = tid & 127;
        int side = tid >> 7;
        int col  = side ? 129 : 0;
        int L    = side ? (S0 + 128) : (S0 - 1);
        L = (L < 0) ? 0 : ((L > 16383) ? 16383 : L);
        int stroke = L >> 5, pt = L & 31;
        int slot = stroke - (n0 - 1);
        int2  ij = sij[slot];
        float2 w = swt[slot];
        float v = w.x * DFb[(size_t)i * 8192 + (size_t)ij.x * NPNT + pt]
                + w.y * DFb[(size_t)i * 8192 + (size_t)ij.y * NPNT + pt];
        int dst = col * 128 + ((((i >> 3) ^ (col & 15))) << 3) + (i & 7);
        Xs[dst] = f32_to_bf16(v);
    }

    // ---- A fragments: coalesced 16B loads from fragment-linear ws ----
    bf16x8v afrag[2][8];
    #pragma unroll
    for (int mt = 0; mt < 2; ++mt) {
        int mt16 = wid + mt * 8;
        #pragma unroll
        for (int ks = 0; ks < 8; ++ks) {
            afrag[mt][ks] = *reinterpret_cast<const bf16x8v*>(
                Aws + (((size_t)(mt16 * 8 + ks)) * 64 + lane) * 8);
        }
    }
    __syncthreads();

    // ---- MFMA main loop: 9 N-tiles x 8 K-steps x 2 M-tiles ----
    #pragma unroll 1
    for (int nt = 0; nt < 9; ++nt) {
        f32x4v acc0 = {0.f, 0.f, 0.f, 0.f};
        f32x4v acc1 = {0.f, 0.f, 0.f, 0.f};
        #pragma unroll
        for (int ks = 0; ks < 8; ++ks) {
            int kb   = ks * 32 + kgrp * 8;
            int half = kb >> 7;
            int i    = kb & 127;
            int col  = nt * 16 + rit + half;
            int src  = col * 128 + ((((i >> 3) ^ (col & 15))) << 3);
            bf16x8v bfrag = *reinterpret_cast<const bf16x8v*>(&Xs[src]);
            acc0 = __builtin_amdgcn_mfma_f32_16x16x32_bf16(afrag[0][ks], bfrag, acc0, 0, 0, 0);
            acc1 = __builtin_amdgcn_mfma_f32_16x16x32_bf16(afrag[1][ks], bfrag, acc1, 0, 0, 0);
        }
        int c = nt * 16 + rit;               // C/D col = lane&15
        int srcl = (lane & 48) | ((lane + 1) & 15);
        #pragma unroll
        for (int q = 0; q < 4; ++q) {
            float a1n = __shfl(acc1[q], srcl, 64);   // C[o+128, c+1] (valid rit<15)
            int o = wid * 16 + kgrp * 4 + q;         // C/D row = (lane>>4)*4+q
            float bias = bnb[o], scale = bns[o], beta = bnt[o];
            size_t rowbase = (((size_t)b * DNOUT + o) << 15) + (size_t)T0;
            if (c < 128) {
                float ye = fast_gelu((acc0[q] + bias) * scale + beta);
                if (rit < 15) {
                    float yo = fast_gelu((a1n + bias) * scale + beta);
                    *reinterpret_cast<float2*>(outd + rowbase + 2 * c) = make_float2(ye, yo);
                } else {
                    outd[rowbase + 2 * c] = ye;
                }
            }
            if (rit == 0 && c >= 1) {
                float yo0 = fast_gelu((acc1[q] + bias) * scale + beta);
                outd[rowbase + 2 * c - 1] = yo0;
            }
        }
    }
}

extern "C" void kernel_launch(void* const* d_in, const int* in_sizes, int n_in,
                              void* d_out, int out_size, void* d_ws, size_t ws_size,
                              hipStream_t stream) {
    const float* sparse_fea   = (const float*)d_in[0];
    const float* dense_fea    = (const float*)d_in[1];
    const float* stk_coor     = (const float*)d_in[2];
    const float* stk_coor_bef = (const float*)d_in[3];
    const float* w_sp     = (const float*)d_in[4];
    const float* b_sp     = (const float*)d_in[5];
    const float* gamma_sp = (const float*)d_in[6];
    const float* beta_sp  = (const float*)d_in[7];
    const float* w_ct     = (const float*)d_in[8];
    const float* b_ct     = (const float*)d_in[9];
    const float* gamma_dn = (const float*)d_in[10];
    const float* beta_dn  = (const float*)d_in[11];
    float* out = (float*)d_out;

    char* ws = (char*)d_ws;
    int2*   idx = (int2*)ws;                          // 64 KB
    float2* wgt = (float2*)(ws + 65536);              // 64 KB
    unsigned short* Aws = (unsigned short*)(ws + 131072);  // 128 KB (total 256 KB)

    knn_kernel<<<dim3(NBEF / 16, NB), 256, 0, stream>>>(stk_coor, stk_coor_bef, idx, wgt);
    prep_a_kernel<<<32, 256, 0, stream>>>(w_ct, Aws);
    sparse_direct_kernel<<<dim3(NBEF / 8, NB), 256, 0, stream>>>(
        sparse_fea, w_sp, idx, wgt, b_sp, gamma_sp, beta_sp, out);
    dense_mfma_kernel<<<dim3(NBEF / 4, NB), 512, 0, stream>>>(
        dense_fea, Aws, b_ct, gamma_dn, beta_dn, idx, wgt, out + SP_ELEMS);
}